// Round 4
// baseline (136.698 us; speedup 1.0000x reference)
//
#include <hip/hip_runtime.h>
#include <hip/hip_bf16.h>

#define CC 64
#define HH 128
#define WW 128
#define OO 576   // C * K * K
#define HW (HH * WW)

typedef __attribute__((ext_vector_type(8))) short short8;
typedef __attribute__((ext_vector_type(4))) float floatx4;

__device__ __forceinline__ unsigned short f2bf(float f) {
    unsigned u = __float_as_uint(f);
    u = (u + 0x7FFFu + ((u >> 16) & 1u)) >> 16;   // RTNE
    return (unsigned short)u;
}

// Prep: permute W_gen rows from o=c*9+t order into Wbp[t][c][k] (bf16) and
// bias into bgp[t][c] (fp32), so chunk t of the main GEMM uses contiguous rows
// and the MFMA C-layout directly matches the combine layout (channel = lane
// row, kk = chunk). 36864 threads.
__global__ void ACDA_prep_kernel(const float* __restrict__ Wg,
                                 const float* __restrict__ bg,
                                 unsigned short* __restrict__ Wbp,
                                 float* __restrict__ bgp) {
    int i = blockIdx.x * 256 + threadIdx.x;
    if (i < OO * CC) {
        int o = i >> 6, k = i & 63;
        int c = o / 9, t = o - 9 * c;
        Wbp[(t * 64 + c) * 64 + k] = f2bf(Wg[i]);
    }
    if (i < OO) {
        int c = i / 9, t = i - 9 * c;
        bgp[t * 64 + c] = bg[i];
    }
}

// Fused filter-gen (bf16 MFMA, bias via C-init) + relu + 3x3 dynamic combine.
// Permuted-A GEMM: chunk t computes F rows o=(wv*16+m)*9+t, so lane (q,l16)
// holds channels wv*16+q*4+reg at kk=t in MFMA C-layout -> combine is pure
// register work. No LDS, no barriers, no cross-lane ops.
__global__ __launch_bounds__(256, 4) void ACDA_main_kernel(
    const float* __restrict__ x, const unsigned short* __restrict__ Wbp,
    const float* __restrict__ bgp, float* __restrict__ out)
{
    const int tid  = threadIdx.x;
    const int wv   = tid >> 6;       // wave id == 16-channel group
    const int lane = tid & 63;
    const int quad = lane >> 4;
    const int l16  = lane & 15;

    const int bid = blockIdx.x;      // 2048 blocks = 8/CU, zero tail
    const int b   = bid & 7;         // batch == XCD slot (L2 locality)
    const int j   = bid >> 3;
    const int seg = j & 1;
    const int h   = (j >> 1) & 127;
    const int w0  = seg << 6;

    const float* __restrict__ xb = x + (size_t)b * CC * HW;

    // ---- B fragments (X tile, bf16) held in registers for all 9 chunks ----
    // B[k][n]: n = lane&15 (pixel), k = quad*8 + j (channel)
    short8 bfrag[4][2];
#pragma unroll
    for (int nt = 0; nt < 4; ++nt) {
#pragma unroll
        for (int ks = 0; ks < 2; ++ks) {
            short8 v;
            const unsigned w = (unsigned)(w0 + nt * 16 + l16);
#pragma unroll
            for (int jj = 0; jj < 8; jj += 2) {
                const unsigned c = (unsigned)(ks * 32 + quad * 8 + jj);
                float f0 = xb[(c * HH + h) * WW + w];
                float f1 = xb[((c + 1) * HH + h) * WW + w];
                __hip_bfloat162 p = __float22bfloat162_rn(make_float2(f0, f1));
                unsigned u;
                __builtin_memcpy(&u, &p, 4);
                v[jj]     = (short)(u & 0xffffu);
                v[jj + 1] = (short)(u >> 16);
            }
            bfrag[nt][ks] = v;
        }
    }

    // ---- clamped per-lane column offsets (element index), per (dj, nt) ----
    unsigned colofs[3][4];
#pragma unroll
    for (int dj = 0; dj < 3; ++dj)
#pragma unroll
        for (int nt = 0; nt < 4; ++nt) {
            int col = w0 + nt * 16 + l16 + dj - 1;
            col = col < 0 ? 0 : (col > 127 ? 127 : col);
            colofs[dj][nt] = (unsigned)col;
        }
    const bool badL = (w0 == 0)  && (l16 == 0);    // only OOB-left lane
    const bool badR = (w0 == 64) && (l16 == 15);   // only OOB-right lane

    // channel base offsets (element index into xb), lane-varying by quad
    unsigned cbase[4];
#pragma unroll
    for (int reg = 0; reg < 4; ++reg)
        cbase[reg] = (unsigned)((wv * 16 + quad * 4 + reg) * HW);

    float oacc[4][4];   // [nt][reg]
#pragma unroll
    for (int nt = 0; nt < 4; ++nt)
#pragma unroll
        for (int reg = 0; reg < 4; ++reg) oacc[nt][reg] = 0.f;

    // ---- 9 chunks: chunk t = kk tap t for all 16 channels of this wave ----
#pragma unroll
    for (int t = 0; t < 9; ++t) {
        const int di  = t / 3;
        const int dj  = t - 3 * di;
        const int row = h + di - 1;
        if (row >= 0 && row < HH) {          // wave-uniform skip at h edges
            // A[m][k]: m = l16 -> filter row (wv*16+m)*9+t via permuted Wbp
            const unsigned short* wrow =
                Wbp + ((t * 64 + wv * 16 + l16) * 64 + quad * 8);
            short8 a0 = *(const short8*)(wrow);
            short8 a1 = *(const short8*)(wrow + 32);
            // bias as MFMA C initializer: C[m][n] = bias[channel(m)]
            floatx4 bq = *(const floatx4*)(bgp + t * 64 + wv * 16 + quad * 4);
            floatx4 acc[4];
#pragma unroll
            for (int nt = 0; nt < 4; ++nt) {
                floatx4 z = bq;
                z = __builtin_amdgcn_mfma_f32_16x16x32_bf16(a0, bfrag[nt][0], z, 0, 0, 0);
                z = __builtin_amdgcn_mfma_f32_16x16x32_bf16(a1, bfrag[nt][1], z, 0, 0, 0);
                acc[nt] = z;
            }
            const unsigned rp = (unsigned)(row * WW);
#pragma unroll
            for (int nt = 0; nt < 4; ++nt)
#pragma unroll
                for (int reg = 0; reg < 4; ++reg) {
                    unsigned idx = cbase[reg] + rp + colofs[dj][nt];
                    float pv = xb[idx];
                    if (dj == 0 && nt == 0) pv = badL ? 0.f : pv;
                    if (dj == 2 && nt == 3) pv = badR ? 0.f : pv;
                    float fv = fmaxf(acc[nt][reg], 0.f);
                    oacc[nt][reg] = fmaf(fv, pv, oacc[nt][reg]);
                }
        }
    }

    // ---- store: lane (q,l16) owns channels wv*16+q*4+reg at px nt*16+l16 ----
    float* ob = out + (size_t)b * CC * HW + h * WW + w0;
#pragma unroll
    for (int nt = 0; nt < 4; ++nt)
#pragma unroll
        for (int reg = 0; reg < 4; ++reg)
            ob[(wv * 16 + quad * 4 + reg) * HW + nt * 16 + l16] = oacc[nt][reg];
}

extern "C" void kernel_launch(void* const* d_in, const int* in_sizes, int n_in,
                              void* d_out, int out_size, void* d_ws, size_t ws_size,
                              hipStream_t stream) {
    const float* x  = (const float*)d_in[0];
    const float* Wg = (const float*)d_in[1];
    const float* bg = (const float*)d_in[2];
    float* out = (float*)d_out;
    unsigned short* Wbp = (unsigned short*)d_ws;              // 73728 B
    float* bgp = (float*)((char*)d_ws + OO * CC * 2);         // 2304 B

    ACDA_prep_kernel<<<dim3((OO * CC + 255) / 256), dim3(256), 0, stream>>>(Wg, bg, Wbp, bgp);
    ACDA_main_kernel<<<dim3(8 * 128 * 2), dim3(256), 0, stream>>>(x, Wbp, bgp, out);
}